// Round 4
// baseline (342.487 us; speedup 1.0000x reference)
//
#include <hip/hip_runtime.h>
#include <math.h>

#define BB 16
#define TT 50
#define AA 3
#define CC 80
#define BA_ 85
#define HH 76
#define WW 76
#define SPAT (HH * WW)          // 5776

__constant__ float c_aw[3] = {1.25f, 2.0f, 4.125f};   // anchors / stride(=8)
__constant__ float c_ah[3] = {1.625f, 3.75f, 2.875f};

__device__ inline float wave_red(float v) {
    #pragma unroll
    for (int off = 32; off; off >>= 1) v += __shfl_down(v, off);
    return v;
}

// 64-thread blocks, one thread per (b,i,j) cell, all 3 anchors per thread.
// Lanes 0..49 decode this batch's targets ONCE (divs/floors/logs hoisted),
// packed into LDS; the per-cell scan is ~10 branchless VALU ops per target
// into scalar registers (no runtime-indexed arrays -> no scratch).
__global__ __launch_bounds__(64) void k_loss(const float* __restrict__ pred,
                                             const float* __restrict__ targets,
                                             float* __restrict__ acc) {
    const int b = blockIdx.y;
    const int lane = threadIdx.x;
    const int s = blockIdx.x * 64 + lane;

    __shared__ unsigned sh_meta[TT];   // valid | best<<1 | ign<<3 | cls<<6
    __shared__ unsigned sh_pos[TT];    // icell | mcell<<16
    __shared__ float sh_gx[TT], sh_gy[TT], sh_tw[TT], sh_th[TT];

    if (lane < TT) {
        const float* tg = targets + ((size_t)b * TT + lane) * 5;
        float gx = tg[0] * WW, gy = tg[1] * HH;
        float gw = tg[2] * WW, gh = tg[3] * HH;
        int cls = (int)tg[4];
        unsigned valid = (gx + gy + gw + gh != 0.0f) ? 1u : 0u;
        int gi = (int)floorf(gx); if (gi == 0) gi = 1;
        int gj = (int)floorf(gy); if (gj == 0) gj = 1;
        float bi = -1.f; int best = 0; unsigned ign = 0;
        #pragma unroll
        for (int a = 0; a < 3; ++a) {
            float aw = c_aw[a], ah = c_ah[a];
            float inter = fminf(gw, aw) * fminf(gh, ah);
            float uni = gw * gh + 1e-16f + aw * ah - inter;
            float iou = inter / uni;
            if (iou > bi) { bi = iou; best = a; }     // first-wins argmax
            if (iou > 0.5f) ign |= (1u << a);
        }
        unsigned icell = (unsigned)(gi * WW + gj);    // noobj[b,:,gi,gj]: H<-gi, W<-gj
        unsigned mcell = (unsigned)(gj * WW + gi);    // main write at H<-gj, W<-gi
        sh_meta[lane] = valid | ((unsigned)best << 1) | (ign << 3) | ((unsigned)cls << 6);
        sh_pos[lane]  = icell | (mcell << 16);
        sh_gx[lane] = gx; sh_gy[lane] = gy;
        sh_tw[lane] = logf(gw / c_aw[best] + 1e-16f);
        sh_th[lane] = logf(gh / c_ah[best] + 1e-16f);
    }
    __syncthreads();

    float s_mse = 0.f, s_bo = 0.f, s_bn = 0.f, s_bc = 0.f, s_co = 0.f, s_cn = 0.f;

    if (s < SPAT) {
        const int i = s / WW, j = s % WW;
        int cleared = 0;                   // bit a: noobj cleared
        int own0 = -1, own1 = -1, own2 = -1;

        for (int t = 0; t < TT; ++t) {
            unsigned ma = sh_meta[t];
            if (!(ma & 1u)) continue;      // uniform across block
            unsigned pos = sh_pos[t];
            bool at_i = (int)(pos & 0xffffu) == s;
            bool at_m = (int)(pos >> 16) == s;
            int best = (int)((ma >> 1) & 3u);
            cleared |= at_i ? (int)((ma >> 3) & 7u) : 0;
            cleared |= at_m ? (1 << best) : 0;
            own0 = (at_m && best == 0) ? t : own0;   // last writer wins
            own1 = (at_m && best == 1) ? t : own1;
            own2 = (at_m && best == 2) ? t : own2;
        }

        const int owns[3] = {own0, own1, own2};      // unrolled -> stays in regs
        #pragma unroll
        for (int a = 0; a < 3; ++a) {
            int own = owns[a];
            bool obj = own >= 0;
            bool noobj = !((cleared >> a) & 1);
            if (!obj && !noobj) continue;

            const float* pc = pred + (size_t)((b * AA + a) * BA_) * SPAT + s;
            float z = pc[4 * SPAT];
            float conf = 1.f / (1.f + expf(-z));
            if (noobj) {
                s_cn += 1.f;
                s_bn += -fmaxf(log1pf(-conf), -100.f);   // tconf = 0
            } else {
                s_co += 1.f;
                s_bo += -fmaxf(logf(conf), -100.f);      // tconf = 1
                float txv = sh_gx[own] - (float)j;       // j == adjusted gi
                float tyv = sh_gy[own] - (float)i;       // i == adjusted gj
                float twv = sh_tw[own];
                float thv = sh_th[own];
                float x  = 1.f / (1.f + expf(-pc[0]));
                float y  = 1.f / (1.f + expf(-pc[SPAT]));
                float w_ = pc[2 * SPAT];
                float h_ = pc[3 * SPAT];
                s_mse += (x - txv) * (x - txv) + (y - tyv) * (y - tyv)
                       + (w_ - twv) * (w_ - twv) + (h_ - thv) * (h_ - thv);

                // tcls = union of one-hots over ALL valid writers of this cell
                unsigned m0 = 0u, m1 = 0u, m2 = 0u;
                for (int t = 0; t < TT; ++t) {
                    unsigned ma = sh_meta[t];
                    bool match = (ma & 1u) &&
                                 ((int)(sh_pos[t] >> 16) == s) &&
                                 ((int)((ma >> 1) & 3u) == a);
                    int c = (int)((ma >> 6) & 127u);
                    unsigned bit = 1u << (c & 31);
                    m0 |= (match && c < 32) ? bit : 0u;
                    m1 |= (match && c >= 32 && c < 64) ? bit : 0u;
                    m2 |= (match && c >= 64) ? bit : 0u;
                }
                #pragma unroll 8
                for (int c = 0; c < CC; ++c) {
                    float zc = pc[(5 + c) * SPAT];
                    float p  = 1.f / (1.f + expf(-zc));
                    float lp  = fmaxf(logf(p), -100.f);
                    float l1p = fmaxf(log1pf(-p), -100.f);
                    unsigned w = (c < 32) ? m0 : ((c < 64) ? m1 : m2);
                    s_bc += ((w >> (c & 31)) & 1) ? -lp : -l1p;
                }
            }
        }
    }

    // single-wave block: wave reduction then one atomicAdd set
    s_mse = wave_red(s_mse); s_bo = wave_red(s_bo); s_bn = wave_red(s_bn);
    s_bc  = wave_red(s_bc);  s_co = wave_red(s_co); s_cn = wave_red(s_cn);
    if (lane == 0) {
        atomicAdd(&acc[0], s_mse); atomicAdd(&acc[1], s_bo);
        atomicAdd(&acc[2], s_bn);  atomicAdd(&acc[3], s_bc);
        atomicAdd(&acc[4], s_co);  atomicAdd(&acc[5], s_cn);
    }
}

__global__ void k_final(const float* __restrict__ acc, float* __restrict__ out) {
    float n_obj   = fmaxf(acc[4], 1.f);
    float n_noobj = fmaxf(acc[5], 1.f);
    out[0] = acc[0] / n_obj                      // x+y+w+h MSE
           + acc[1] / n_obj                      // OBJ_SCALE * conf-obj BCE
           + 100.f * (acc[2] / n_noobj)          // NOOBJ_SCALE * conf-noobj BCE
           + acc[3] / (n_obj * (float)CC);       // class BCE
}

extern "C" void kernel_launch(void* const* d_in, const int* in_sizes, int n_in,
                              void* d_out, int out_size, void* d_ws, size_t ws_size,
                              hipStream_t stream) {
    const float* pred    = (const float*)d_in[0];
    const float* targets = (const float*)d_in[1];
    float* out = (float*)d_out;
    float* acc = (float*)d_ws;      // 6 floats used

    hipMemsetAsync(acc, 0, 64, stream);

    dim3 grid((SPAT + 63) / 64, BB);   // 91 x 16 = 1456 single-wave blocks
    k_loss<<<grid, 64, 0, stream>>>(pred, targets, acc);
    k_final<<<1, 1, 0, stream>>>(acc, out);
}

// Round 6
// 187.366 us; speedup vs baseline: 1.8279x; 1.8279x over previous
//
#include <hip/hip_runtime.h>
#include <math.h>

#define BB 16
#define TT 50
#define AA 3
#define CC 80
#define BA_ 85
#define HH 76
#define WW 76
#define SPAT (HH * WW)          // 5776
#define BMW 544                 // bitmap words per batch (ceil(3*5776/32)=542, padded)
#define NREC_MAX (BB * TT)      // 800
#define NF4 (BB * AA * (SPAT / 4))   // 69312 float4 conf elements

__constant__ float c_aw[3] = {1.25f, 2.0f, 4.125f};   // anchors / stride(=8)
__constant__ float c_ah[3] = {1.625f, 3.75f, 2.875f};

struct Rec {                    // 32 B
    int base;                   // pred element offset of (b, best, cell)
    float tx, ty, tw, th;
    unsigned m0, m1, m2;        // class one-hot union
};

__device__ inline float wave_red(float v) {
    #pragma unroll
    for (int off = 32; off; off >>= 1) v += __shfl_down(v, off);
    return v;
}

// ---------------------------------------------------------------------------
// Per-batch target decode: cleared-cell bitmap + compacted owner records.
// ---------------------------------------------------------------------------
__global__ __launch_bounds__(64) void k_build(const float* __restrict__ targets,
                                              unsigned* __restrict__ bitmaps,
                                              int* __restrict__ cnt,
                                              Rec* __restrict__ recs) {
    const int b = blockIdx.x;
    const int lane = threadIdx.x;

    __shared__ unsigned bm[BMW];
    __shared__ int sh_valid[TT], sh_best[TT], sh_mcell[TT], sh_cls[TT];

    for (int w = lane; w < BMW; w += 64) bm[w] = 0u;

    int valid = 0, best = 0, mcell = 0, icell = 0, ign = 0, cls = 0;
    float txv = 0.f, tyv = 0.f, gw = 0.f, gh = 0.f;
    if (lane < TT) {
        const float* tg = targets + ((size_t)b * TT + lane) * 5;
        float gx = tg[0] * WW, gy = tg[1] * HH;
        gw = tg[2] * WW; gh = tg[3] * HH;
        cls = (int)tg[4];
        valid = (gx + gy + gw + gh != 0.0f) ? 1 : 0;
        int gi = (int)floorf(gx); if (gi == 0) gi = 1;
        int gj = (int)floorf(gy); if (gj == 0) gj = 1;
        float bi = -1.f;
        #pragma unroll
        for (int a = 0; a < 3; ++a) {
            float inter = fminf(gw, c_aw[a]) * fminf(gh, c_ah[a]);
            float uni = gw * gh + 1e-16f + c_aw[a] * c_ah[a] - inter;
            float iou = inter / uni;
            if (iou > bi) { bi = iou; best = a; }     // first-wins argmax
            if (iou > 0.5f) ign |= 1 << a;
        }
        icell = gi * WW + gj;   // ignore-clear at noobj[b,:,gi,gj] -> H<-gi, W<-gj
        mcell = gj * WW + gi;   // main write at (b,best,gj,gi)     -> H<-gj, W<-gi
        txv = gx - (float)gi;
        tyv = gy - (float)gj;
        sh_valid[lane] = valid; sh_best[lane] = best;
        sh_mcell[lane] = mcell; sh_cls[lane]  = cls;
    }
    __syncthreads();

    if (lane < TT && valid) {
        #pragma unroll
        for (int a = 0; a < 3; ++a)
            if ((ign >> a) & 1) {
                int bit = a * SPAT + icell;
                atomicOr(&bm[bit >> 5], 1u << (bit & 31));
            }
        int mb = best * SPAT + mcell;
        atomicOr(&bm[mb >> 5], 1u << (mb & 31));

        // owner iff no LATER valid target writes the same (cell, anchor)
        bool owner = true;
        for (int t2 = lane + 1; t2 < TT; ++t2)
            if (sh_valid[t2] && sh_mcell[t2] == mcell && sh_best[t2] == best) {
                owner = false; break;
            }
        if (owner) {
            unsigned m0 = 0u, m1 = 0u, m2 = 0u;   // tcls union over ALL writers
            for (int t2 = 0; t2 < TT; ++t2)
                if (sh_valid[t2] && sh_mcell[t2] == mcell && sh_best[t2] == best) {
                    int c = sh_cls[t2];
                    if (c < 32) m0 |= 1u << c;
                    else if (c < 64) m1 |= 1u << (c - 32);
                    else m2 |= 1u << (c - 64);
                }
            int slot = atomicAdd(cnt, 1);
            Rec r;
            r.base = ((b * AA + best) * BA_) * SPAT + mcell;
            r.tx = txv; r.ty = tyv;
            r.tw = logf(gw / c_aw[best] + 1e-16f);
            r.th = logf(gh / c_ah[best] + 1e-16f);
            r.m0 = m0; r.m1 = m1; r.m2 = m2;
            recs[slot] = r;
        }
    }
    __syncthreads();
    for (int w = lane; w < BMW; w += 64) bitmaps[b * BMW + w] = bm[w];
}

// ---------------------------------------------------------------------------
// Dense conf-noobj BCE over all cells (float4 on the conf channel).
// ---------------------------------------------------------------------------
__global__ __launch_bounds__(256) void k_noobj(const float* __restrict__ pred,
                                               const unsigned* __restrict__ bitmaps,
                                               float* __restrict__ acc) {
    int f = blockIdx.x * 256 + threadIdx.x;
    float s_bn = 0.f, s_cn = 0.f;
    if (f < NF4) {
        int plane = f / (SPAT / 4);          // 0..47
        int q = f % (SPAT / 4);
        int b = plane / AA, a = plane % AA;
        int s0 = q * 4;
        const float4 z4 = *reinterpret_cast<const float4*>(
            pred + (size_t)((b * AA + a) * BA_ + 4) * SPAT + s0);
        int idx = a * SPAT + s0;             // idx%4==0 -> 4 bits in one word
        unsigned bits = (bitmaps[b * BMW + (idx >> 5)] >> (idx & 31)) & 0xFu;
        float zs[4] = {z4.x, z4.y, z4.z, z4.w};
        #pragma unroll
        for (int k = 0; k < 4; ++k)
            if (!((bits >> k) & 1)) {
                float conf = 1.f / (1.f + expf(-zs[k]));
                s_cn += 1.f;
                s_bn += -fmaxf(log1pf(-conf), -100.f);   // tconf = 0
            }
    }
    s_bn = wave_red(s_bn); s_cn = wave_red(s_cn);
    __shared__ float lds[4][2];
    int wave = threadIdx.x >> 6;
    if ((threadIdx.x & 63) == 0) { lds[wave][0] = s_bn; lds[wave][1] = s_cn; }
    __syncthreads();
    if (threadIdx.x == 0) {
        atomicAdd(&acc[2], lds[0][0] + lds[1][0] + lds[2][0] + lds[3][0]);
        atomicAdd(&acc[5], lds[0][1] + lds[1][1] + lds[2][1] + lds[3][1]);
    }
}

// ---------------------------------------------------------------------------
// One wave per owner cell; lane = channel. 85 channels via 2 lane-parallel loads.
// ---------------------------------------------------------------------------
__global__ __launch_bounds__(64) void k_obj(const float* __restrict__ pred,
                                            const int* __restrict__ cnt,
                                            const Rec* __restrict__ recs,
                                            float* __restrict__ acc) {
    int w = blockIdx.x;
    if (w >= *cnt) return;
    Rec r = recs[w];
    int lane = threadIdx.x;
    float s_mse = 0.f, s_bo = 0.f, s_bc = 0.f;

    {   // channel c = lane (0..63)
        float z = pred[(size_t)r.base + (size_t)lane * SPAT];
        if (lane == 0) { float x = 1.f/(1.f+expf(-z)); s_mse += (x-r.tx)*(x-r.tx); }
        else if (lane == 1) { float y = 1.f/(1.f+expf(-z)); s_mse += (y-r.ty)*(y-r.ty); }
        else if (lane == 2) { s_mse += (z-r.tw)*(z-r.tw); }
        else if (lane == 3) { s_mse += (z-r.th)*(z-r.th); }
        else if (lane == 4) { float cf = 1.f/(1.f+expf(-z)); s_bo += -fmaxf(logf(cf), -100.f); }
        else {               // class index ci = lane-5 in [0,58]
            int ci = lane - 5;
            unsigned wd = (ci < 32) ? r.m0 : r.m1;
            int tcv = (wd >> (ci & 31)) & 1;
            float p = 1.f / (1.f + expf(-z));
            s_bc += tcv ? -fmaxf(logf(p), -100.f) : -fmaxf(log1pf(-p), -100.f);
        }
    }
    if (lane < BA_ - 64) {   // channel 64+lane -> class ci = 59+lane in [59,79]
        float z = pred[(size_t)r.base + (size_t)(64 + lane) * SPAT];
        int ci = 59 + lane;
        unsigned wd = (ci < 64) ? r.m1 : r.m2;
        int tcv = (wd >> (ci & 31)) & 1;
        float p = 1.f / (1.f + expf(-z));
        s_bc += tcv ? -fmaxf(logf(p), -100.f) : -fmaxf(log1pf(-p), -100.f);
    }

    s_mse = wave_red(s_mse); s_bo = wave_red(s_bo); s_bc = wave_red(s_bc);
    if (lane == 0) {
        atomicAdd(&acc[0], s_mse); atomicAdd(&acc[1], s_bo);
        atomicAdd(&acc[3], s_bc);  atomicAdd(&acc[4], 1.f);   // n_obj: one per owner cell
    }
}

__global__ void k_final(const float* __restrict__ acc, float* __restrict__ out) {
    float n_obj   = fmaxf(acc[4], 1.f);
    float n_noobj = fmaxf(acc[5], 1.f);
    out[0] = acc[0] / n_obj                      // x+y+w+h MSE
           + acc[1] / n_obj                      // OBJ_SCALE * conf-obj BCE
           + 100.f * (acc[2] / n_noobj)          // NOOBJ_SCALE * conf-noobj BCE
           + acc[3] / (n_obj * (float)CC);       // class BCE
}

extern "C" void kernel_launch(void* const* d_in, const int* in_sizes, int n_in,
                              void* d_out, int out_size, void* d_ws, size_t ws_size,
                              hipStream_t stream) {
    const float* pred    = (const float*)d_in[0];
    const float* targets = (const float*)d_in[1];
    float* out = (float*)d_out;
    char* ws = (char*)d_ws;

    // ws layout: [0,64) acc | [64,68) cnt | [128, 128+800*32) recs |
    //            [25728, 25728+16*544*4=60544) bitmaps.  ~60 KB total.
    float*    acc     = (float*)ws;
    int*      cnt     = (int*)(ws + 64);
    Rec*      recs    = (Rec*)(ws + 128);
    unsigned* bitmaps = (unsigned*)(ws + 128 + NREC_MAX * sizeof(Rec));

    hipMemsetAsync(ws, 0, 128, stream);
    k_build<<<BB, 64, 0, stream>>>(targets, bitmaps, cnt, recs);
    k_noobj<<<(NF4 + 255) / 256, 256, 0, stream>>>(pred, bitmaps, acc);
    k_obj<<<NREC_MAX, 64, 0, stream>>>(pred, cnt, recs, acc);
    k_final<<<1, 1, 0, stream>>>(acc, out);
}

// Round 7
// 164.265 us; speedup vs baseline: 2.0850x; 1.1406x over previous
//
#include <hip/hip_runtime.h>
#include <math.h>

#define BB 16
#define TT 50
#define AA 3
#define CC 80
#define BA_ 85
#define HH 76
#define WW 76
#define SPAT (HH * WW)          // 5776
#define BMW 544                 // bitmap words (ceil(3*5776/32)=542, padded)
#define NQ (SPAT / 4)           // 1444 float4 per (b,a) conf plane
#define NF4 (BB * AA * NQ)      // 69312
#define NOB ((NF4 + 255) / 256) // 271 dense-noobj blocks
#define PB_OFF 544              // float offset of build partials in part[]

__constant__ float c_aw[3] = {1.25f, 2.0f, 4.125f};   // anchors / stride(=8)
__constant__ float c_ah[3] = {1.625f, 3.75f, 2.875f};

__device__ inline float wave_red(float v) {
    #pragma unroll
    for (int off = 32; off; off >>= 1) v += __shfl_down(v, off);
    return v;
}

// ---------------------------------------------------------------------------
// K1: blocks 0..NOB-1   : dense conf-BCE partials over ALL cells (no mask)
//     blocks NOB..NOB+15: per-batch build + obj wave-work + cleared-cell
//                         correction (subtract what the dense pass added).
// All partials written unconditionally -> no zero-init / memset needed.
// part layout (floats): [0,542) dense {bn,cn} pairs; [544,544+96) build
// {mse, bo, bc, n_obj, bn_sub, cn_sub} per batch.
// ---------------------------------------------------------------------------
__global__ __launch_bounds__(256) void k_main(const float* __restrict__ pred,
                                              const float* __restrict__ targets,
                                              float* __restrict__ part) {
    const int bx = blockIdx.x;
    const int tid = threadIdx.x;
    const int wave = tid >> 6, lane = tid & 63;

    if (bx < NOB) {
        // ---- dense conf BCE over every (b,a,cell), tconf=0 form ----
        int f = bx * 256 + tid;
        float s_bn = 0.f, s_cn = 0.f;
        if (f < NF4) {
            int plane = f / NQ;              // b*AA + a
            int q = f - plane * NQ;
            const float4 z4 = *reinterpret_cast<const float4*>(
                pred + (size_t)(plane * BA_ + 4) * SPAT + q * 4);
            float zs[4] = {z4.x, z4.y, z4.z, z4.w};
            #pragma unroll
            for (int k = 0; k < 4; ++k) {
                float conf = 1.f / (1.f + expf(-zs[k]));
                s_bn += -fmaxf(log1pf(-conf), -100.f);
            }
            s_cn = 4.f;
        }
        s_bn = wave_red(s_bn); s_cn = wave_red(s_cn);
        __shared__ float r2[4][2];
        if (lane == 0) { r2[wave][0] = s_bn; r2[wave][1] = s_cn; }
        __syncthreads();
        if (tid == 0) {
            part[bx * 2 + 0] = r2[0][0] + r2[1][0] + r2[2][0] + r2[3][0];
            part[bx * 2 + 1] = r2[0][1] + r2[1][1] + r2[2][1] + r2[3][1];
        }
        return;
    }

    // ---- build + obj + correction for batch b ----
    const int b = bx - NOB;
    __shared__ unsigned bm[BMW];
    __shared__ int sh_valid[TT], sh_best[TT], sh_mcell[TT], sh_cls[TT], sh_owner[TT];
    __shared__ float sh_tx[TT], sh_ty[TT], sh_tw[TT], sh_th[TT];
    __shared__ unsigned sh_m0[TT], sh_m1[TT], sh_m2[TT];
    __shared__ float red[4][6];

    for (int w = tid; w < BMW; w += 256) bm[w] = 0u;

    int valid = 0, best = 0, mcell = 0, icell = 0, ign = 0;
    if (tid < TT) {
        const float* tg = targets + ((size_t)b * TT + tid) * 5;
        float gx = tg[0] * WW, gy = tg[1] * HH;
        float gw = tg[2] * WW, gh = tg[3] * HH;
        int cls = (int)tg[4];
        valid = (gx + gy + gw + gh != 0.0f) ? 1 : 0;
        int gi = (int)floorf(gx); if (gi == 0) gi = 1;
        int gj = (int)floorf(gy); if (gj == 0) gj = 1;
        float bi = -1.f;
        #pragma unroll
        for (int a = 0; a < 3; ++a) {
            float inter = fminf(gw, c_aw[a]) * fminf(gh, c_ah[a]);
            float uni = gw * gh + 1e-16f + c_aw[a] * c_ah[a] - inter;
            float iou = inter / uni;
            if (iou > bi) { bi = iou; best = a; }     // first-wins argmax
            if (iou > 0.5f) ign |= 1 << a;
        }
        icell = gi * WW + gj;   // ignore-clear at noobj[b,:,gi,gj] -> H<-gi, W<-gj
        mcell = gj * WW + gi;   // main write at (b,best,gj,gi)     -> H<-gj, W<-gi
        sh_valid[tid] = valid; sh_best[tid] = best;
        sh_mcell[tid] = mcell; sh_cls[tid] = cls;
        sh_tx[tid] = gx - (float)gi;
        sh_ty[tid] = gy - (float)gj;
        sh_tw[tid] = logf(gw / c_aw[best] + 1e-16f);
        sh_th[tid] = logf(gh / c_ah[best] + 1e-16f);
    }
    __syncthreads();

    if (tid < TT) {
        int owner = 0;
        if (valid) {
            #pragma unroll
            for (int a = 0; a < 3; ++a)
                if ((ign >> a) & 1) {
                    int bit = a * SPAT + icell;
                    atomicOr(&bm[bit >> 5], 1u << (bit & 31));
                }
            int mb = best * SPAT + mcell;
            atomicOr(&bm[mb >> 5], 1u << (mb & 31));

            owner = 1;   // owner iff no LATER valid target hits same (cell,anchor)
            for (int t2 = tid + 1; t2 < TT; ++t2)
                if (sh_valid[t2] && sh_mcell[t2] == mcell && sh_best[t2] == best) {
                    owner = 0; break;
                }
            if (owner) {
                unsigned m0 = 0u, m1 = 0u, m2 = 0u;   // tcls union over ALL writers
                for (int t2 = 0; t2 < TT; ++t2)
                    if (sh_valid[t2] && sh_mcell[t2] == mcell && sh_best[t2] == best) {
                        int c = sh_cls[t2];
                        if (c < 32) m0 |= 1u << c;
                        else if (c < 64) m1 |= 1u << (c - 32);
                        else m2 |= 1u << (c - 64);
                    }
                sh_m0[tid] = m0; sh_m1[tid] = m1; sh_m2[tid] = m2;
            }
        }
        sh_owner[tid] = owner;
    }
    __syncthreads();

    // ---- obj: wave-parallel channels, recs distributed across 4 waves ----
    float s_mse = 0.f, s_bo = 0.f, s_bc = 0.f, s_no = 0.f;
    for (int r = wave; r < TT; r += 4) {
        if (!sh_owner[r]) continue;
        int base = ((b * AA + sh_best[r]) * BA_) * SPAT + sh_mcell[r];
        unsigned m0 = sh_m0[r], m1 = sh_m1[r], m2 = sh_m2[r];
        float z = pred[(size_t)base + (size_t)lane * SPAT];
        if (lane == 0) {
            float x = 1.f / (1.f + expf(-z));
            s_mse += (x - sh_tx[r]) * (x - sh_tx[r]);
            s_no += 1.f;
        } else if (lane == 1) {
            float y = 1.f / (1.f + expf(-z));
            s_mse += (y - sh_ty[r]) * (y - sh_ty[r]);
        } else if (lane == 2) {
            s_mse += (z - sh_tw[r]) * (z - sh_tw[r]);
        } else if (lane == 3) {
            s_mse += (z - sh_th[r]) * (z - sh_th[r]);
        } else if (lane == 4) {
            float cf = 1.f / (1.f + expf(-z));
            s_bo += -fmaxf(logf(cf), -100.f);          // tconf = 1
        } else {                                        // class ci = lane-5 in [0,58]
            int ci = lane - 5;
            unsigned wd = (ci < 32) ? m0 : m1;
            int tcv = (wd >> (ci & 31)) & 1;
            float p = 1.f / (1.f + expf(-z));
            s_bc += tcv ? -fmaxf(logf(p), -100.f) : -fmaxf(log1pf(-p), -100.f);
        }
        if (lane < BA_ - 64) {                          // ci = 59+lane in [59,79]
            float z2 = pred[(size_t)base + (size_t)(64 + lane) * SPAT];
            int ci = 59 + lane;
            unsigned wd = (ci < 64) ? m1 : m2;
            int tcv = (wd >> (ci & 31)) & 1;
            float p = 1.f / (1.f + expf(-z2));
            s_bc += tcv ? -fmaxf(logf(p), -100.f) : -fmaxf(log1pf(-p), -100.f);
        }
    }

    // ---- correction: subtract dense-pass terms at cleared cells ----
    float s_bs = 0.f, s_cs = 0.f;
    for (int w = tid; w < BMW; w += 256) {
        unsigned bits = bm[w];
        while (bits) {
            int bit = __ffs(bits) - 1; bits &= bits - 1;
            int idx = w * 32 + bit;          // a*SPAT + s
            int a = idx / SPAT;
            int s = idx - a * SPAT;
            float z = pred[(size_t)((b * AA + a) * BA_ + 4) * SPAT + s];
            float conf = 1.f / (1.f + expf(-z));
            s_bs += -fmaxf(log1pf(-conf), -100.f);
            s_cs += 1.f;
        }
    }

    s_mse = wave_red(s_mse); s_bo = wave_red(s_bo); s_bc = wave_red(s_bc);
    s_no  = wave_red(s_no);  s_bs = wave_red(s_bs); s_cs = wave_red(s_cs);
    if (lane == 0) {
        red[wave][0] = s_mse; red[wave][1] = s_bo; red[wave][2] = s_bc;
        red[wave][3] = s_no;  red[wave][4] = s_bs; red[wave][5] = s_cs;
    }
    __syncthreads();
    if (tid == 0) {
        #pragma unroll
        for (int k = 0; k < 6; ++k)
            part[PB_OFF + b * 6 + k] =
                red[0][k] + red[1][k] + red[2][k] + red[3][k];
    }
}

// ---------------------------------------------------------------------------
// K2: reduce all partials, compute final loss.
// ---------------------------------------------------------------------------
__global__ __launch_bounds__(256) void k_final(const float* __restrict__ part,
                                               float* __restrict__ out) {
    const int tid = threadIdx.x;
    const int wave = tid >> 6, lane = tid & 63;
    float v_mse = 0.f, v_bo = 0.f, v_bn = 0.f, v_bc = 0.f, v_no = 0.f, v_cn = 0.f;

    for (int i = tid; i < NOB; i += 256) {
        v_bn += part[i * 2 + 0];
        v_cn += part[i * 2 + 1];
    }
    for (int i = tid; i < BB; i += 256) {
        const float* p = part + PB_OFF + i * 6;
        v_mse += p[0]; v_bo += p[1]; v_bc += p[2];
        v_no  += p[3]; v_bn -= p[4]; v_cn -= p[5];   // subtract cleared cells
    }

    v_mse = wave_red(v_mse); v_bo = wave_red(v_bo); v_bn = wave_red(v_bn);
    v_bc  = wave_red(v_bc);  v_no = wave_red(v_no); v_cn = wave_red(v_cn);

    __shared__ float red[4][6];
    if (lane == 0) {
        red[wave][0] = v_mse; red[wave][1] = v_bo; red[wave][2] = v_bn;
        red[wave][3] = v_bc;  red[wave][4] = v_no; red[wave][5] = v_cn;
    }
    __syncthreads();
    if (tid == 0) {
        float m[6];
        #pragma unroll
        for (int k = 0; k < 6; ++k)
            m[k] = red[0][k] + red[1][k] + red[2][k] + red[3][k];
        float n_obj   = fmaxf(m[4], 1.f);
        float n_noobj = fmaxf(m[5], 1.f);
        out[0] = m[0] / n_obj                      // x+y+w+h MSE
               + m[1] / n_obj                      // OBJ_SCALE * conf-obj BCE
               + 100.f * (m[2] / n_noobj)          // NOOBJ_SCALE * conf-noobj BCE
               + m[3] / (n_obj * (float)CC);       // class BCE
    }
}

extern "C" void kernel_launch(void* const* d_in, const int* in_sizes, int n_in,
                              void* d_out, int out_size, void* d_ws, size_t ws_size,
                              hipStream_t stream) {
    const float* pred    = (const float*)d_in[0];
    const float* targets = (const float*)d_in[1];
    float* out  = (float*)d_out;
    float* part = (float*)d_ws;     // ~2.6 KB used; fully rewritten every launch

    k_main<<<NOB + BB, 256, 0, stream>>>(pred, targets, part);
    k_final<<<1, 256, 0, stream>>>(part, out);
}